// Round 6
// baseline (831.131 us; speedup 1.0000x reference)
//
#include <hip/hip_runtime.h>
#include <hip/hip_bf16.h>
#include <math.h>

typedef __attribute__((ext_vector_type(8))) short short8;
typedef __attribute__((ext_vector_type(4))) float floatx4;

// ---------------- row_ptr: lower_bound per node over sorted edge_row ----------------
__global__ void rowptr_k(const int* __restrict__ erow, int* __restrict__ rp, int n, int e) {
    int i = blockIdx.x * blockDim.x + threadIdx.x;
    if (i > n) return;
    int lo = 0, hi = e;
    while (lo < hi) {
        int mid = (lo + hi) >> 1;
        if (erow[mid] < i) lo = mid + 1; else hi = mid;
    }
    rp[i] = lo;
}

__global__ void zero_k(float* __restrict__ p) {
    int i = threadIdx.x;
    if (i < 224) p[i] = 0.f;
}

__device__ __forceinline__ float elu_f(float t) {
    return t > 0.f ? t : expm1f(t);
}

__device__ __forceinline__ unsigned short f2bf(float f) {
    unsigned int u = __float_as_uint(f);
    u = (u + 0x7FFFu + ((u >> 16) & 1u)) >> 16;
    return (unsigned short)u;
}

// pack two fp32 -> packed bf16x2 (lo in low half), RNE
__device__ __forceinline__ unsigned int f2bf2(float lo, float hi) {
    unsigned int a = __float_as_uint(lo);
    unsigned int b = __float_as_uint(hi);
    a = (a + 0x7FFFu + ((a >> 16) & 1u)) >> 16;
    b = (b + 0x7FFFu + ((b >> 16) & 1u)) & 0xFFFF0000u;
    return a | b;
}

__device__ __forceinline__ float bflo(unsigned int d) { return __uint_as_float(d << 16); }
__device__ __forceinline__ float bfhi(unsigned int d) { return __uint_as_float(d & 0xFFFF0000u); }

// ---------------- W1 -> bf16 transposed [n][k] = [64][512] --------------------------
__global__ __launch_bounds__(256) void w1bf_k(const float* __restrict__ W,
                                              unsigned short* __restrict__ Wb) {
    int idx = blockIdx.x * 256 + threadIdx.x;  // 0..32767
    int n = idx >> 9, k = idx & 511;
    Wb[idx] = f2bf(W[(long)k * 64 + n]);
}

// ---------------- W2/W3 -> bf16 transposed ------------------------------------------
__global__ __launch_bounds__(256) void wsmall_k(const float* __restrict__ W2,
                                                const float* __restrict__ W3,
                                                unsigned short* __restrict__ Wb2,
                                                unsigned short* __restrict__ Wb3) {
    int idx = blockIdx.x * 256 + threadIdx.x;  // 0..2047
    if (idx < 2048) {  // Wb2: [32][64]
        int n = idx >> 6, k = idx & 63;
        Wb2[idx] = f2bf(W2[(long)k * 32 + n]);
    }
    if (idx < 512) {   // Wb3: [16][32]
        int n = idx >> 5, k = idx & 31;
        Wb3[idx] = f2bf(W3[(long)k * 16 + n]);
    }
}

// ---------------- GEMM1 (MFMA bf16, streaming): Abf[N x 64] = X @ W1 ----------------
__global__ __launch_bounds__(256) void gemm1_mfma_k(const float* __restrict__ X,
                                                    const unsigned short* __restrict__ Wb,
                                                    unsigned short* __restrict__ out, int nrows) {
    const int lane = threadIdx.x & 63;
    const int wid  = threadIdx.x >> 6;
    const int lrow = lane & 15;
    const int quad = lane >> 4;
    const int m0   = (blockIdx.x * 4 + wid) * 16;
    if (m0 >= nrows) return;  // wave-uniform

    int arow = m0 + lrow;
    if (arow >= nrows) arow = nrows - 1;
    const float* __restrict__ xrow = X + (long)arow * 512 + quad * 8;
    const unsigned short* __restrict__ brow = Wb + lrow * 512 + quad * 8;

    floatx4 acc[4];
#pragma unroll
    for (int ni = 0; ni < 4; ++ni) acc[ni] = (floatx4){0.f, 0.f, 0.f, 0.f};

    float4 ca0 = *(const float4*)(xrow + 0);
    float4 ca1 = *(const float4*)(xrow + 4);
    short8 cb[4];
#pragma unroll
    for (int ni = 0; ni < 4; ++ni) cb[ni] = *(const short8*)(brow + ni * 8192);

#pragma unroll
    for (int kc = 0; kc < 16; ++kc) {
        float4 na0, na1;
        short8 nb[4];
        if (kc < 15) {
            const float* xp = xrow + (kc + 1) * 32;
            na0 = *(const float4*)(xp + 0);
            na1 = *(const float4*)(xp + 4);
#pragma unroll
            for (int ni = 0; ni < 4; ++ni)
                nb[ni] = *(const short8*)(brow + ni * 8192 + (kc + 1) * 32);
        }
        union { short8 s; unsigned int u[4]; } af;
        af.u[0] = f2bf2(ca0.x, ca0.y);
        af.u[1] = f2bf2(ca0.z, ca0.w);
        af.u[2] = f2bf2(ca1.x, ca1.y);
        af.u[3] = f2bf2(ca1.z, ca1.w);
#pragma unroll
        for (int ni = 0; ni < 4; ++ni)
            acc[ni] = __builtin_amdgcn_mfma_f32_16x16x32_bf16(af.s, cb[ni], acc[ni], 0, 0, 0);
        if (kc < 15) {
            ca0 = na0; ca1 = na1;
#pragma unroll
            for (int ni = 0; ni < 4; ++ni) cb[ni] = nb[ni];
        }
    }

    // C/D layout: col = lane&15, row = quad*4 + reg
#pragma unroll
    for (int r = 0; r < 4; ++r) {
        int gr = m0 + quad * 4 + r;
        if (gr < nrows) {
#pragma unroll
            for (int ni = 0; ni < 4; ++ni)
                out[(long)gr * 64 + ni * 16 + lrow] = f2bf(acc[ni][r]);
        }
    }
}

// ---------------- layers 2-3: streaming MFMA bf16 with fused BN+ELU on input --------
// out[N x NSTR] (bf16) = bn_elu(H[N x K]) @ W[K x NC], Wb transposed [NF*16][KP] bf16.
template<int K, int KP, int NF, int NSTR>
__global__ __launch_bounds__(256) void gemmS_k(const unsigned short* __restrict__ H,
                                               const unsigned short* __restrict__ Wb,
                                               const float* __restrict__ stats,
                                               const float* __restrict__ gamma,
                                               const float* __restrict__ beta,
                                               unsigned short* __restrict__ out,
                                               int nrows) {
    __shared__ __align__(16) float scs[K];
    __shared__ __align__(16) float shs[K];
    const int tid = threadIdx.x;
    if (tid < K) {
        float s1 = stats[tid], s2 = stats[K + tid];
        float mean = s1 / (float)nrows;
        float var  = s2 / (float)nrows - mean * mean;
        float rstd = rsqrtf(var + 1e-5f);
        float scl  = gamma[tid] * rstd;
        scs[tid] = scl;
        shs[tid] = beta[tid] - mean * scl;
    }
    __syncthreads();

    const int lane = tid & 63;
    const int wid  = tid >> 6;
    const int lrow = lane & 15;
    const int quad = lane >> 4;
    const int m0   = (blockIdx.x * 4 + wid) * 16;
    if (m0 >= nrows) return;  // after barrier: safe

    int arow = m0 + lrow;
    if (arow >= nrows) arow = nrows - 1;
    const unsigned short* __restrict__ hrow = H + (long)arow * K;

    floatx4 acc[NF];
#pragma unroll
    for (int ni = 0; ni < NF; ++ni) acc[ni] = (floatx4){0.f, 0.f, 0.f, 0.f};

#pragma unroll
    for (int kc = 0; kc < KP; kc += 32) {
        const int k8 = kc + quad * 8;
        union { short8 s; unsigned int u[4]; } af;
        if (k8 < K) {
            uint4 d = *(const uint4*)(hrow + k8);
            float4 sc0 = *(const float4*)&scs[k8];
            float4 sc1 = *(const float4*)&scs[k8 + 4];
            float4 sh0 = *(const float4*)&shs[k8];
            float4 sh1 = *(const float4*)&shs[k8 + 4];
            float f0 = elu_f(bflo(d.x) * sc0.x + sh0.x);
            float f1 = elu_f(bfhi(d.x) * sc0.y + sh0.y);
            float f2 = elu_f(bflo(d.y) * sc0.z + sh0.z);
            float f3 = elu_f(bfhi(d.y) * sc0.w + sh0.w);
            float f4 = elu_f(bflo(d.z) * sc1.x + sh1.x);
            float f5 = elu_f(bfhi(d.z) * sc1.y + sh1.y);
            float f6 = elu_f(bflo(d.w) * sc1.z + sh1.z);
            float f7 = elu_f(bfhi(d.w) * sc1.w + sh1.w);
            af.u[0] = f2bf2(f0, f1);
            af.u[1] = f2bf2(f2, f3);
            af.u[2] = f2bf2(f4, f5);
            af.u[3] = f2bf2(f6, f7);
        } else {
            af.u[0] = af.u[1] = af.u[2] = af.u[3] = 0u;
        }
#pragma unroll
        for (int ni = 0; ni < NF; ++ni) {
            short8 bf = *(const short8*)&Wb[(ni * 16 + lrow) * KP + k8];
            acc[ni] = __builtin_amdgcn_mfma_f32_16x16x32_bf16(af.s, bf, acc[ni], 0, 0, 0);
        }
    }

#pragma unroll
    for (int r = 0; r < 4; ++r) {
        int gr = m0 + quad * 4 + r;
        if (gr < nrows) {
#pragma unroll
            for (int ni = 0; ni < NF; ++ni)
                out[(long)gr * NSTR + ni * 16 + lrow] = f2bf(acc[ni][r]);
        }
    }
}

// ---------------- SpMM F=64 (unbucketed control): out = A * sup, bf16 ---------------
__global__ __launch_bounds__(256) void spmm64_k(const int* __restrict__ rp,
                                                const int* __restrict__ ecol,
                                                const float* __restrict__ ev,
                                                const unsigned short* __restrict__ sup,
                                                unsigned short* __restrict__ out, int n) {
    const int lane = threadIdx.x & 63;
    const int node = (blockIdx.x * blockDim.x + threadIdx.x) >> 6;
    if (node >= n) return;
    int s = __builtin_amdgcn_readfirstlane(rp[node]);
    int e = __builtin_amdgcn_readfirstlane(rp[node + 1]);
    const int g = lane >> 4, p = lane & 15;  // 4 groups x 16 lanes
    float a0 = 0.f, a1 = 0.f, a2 = 0.f, a3 = 0.f;
    for (int i = s; i < e; i += 16) {
#pragma unroll
        for (int b = 0; b < 4; ++b) {
            int idx = i + b * 4 + g;
            int cidx = idx < e ? idx : e - 1;  // e>s inside loop -> safe
            int col = ecol[cidx];
            float v = ev[cidx];
            if (idx >= e) v = 0.f;
            uint2 d = *(const uint2*)((const char*)sup + (unsigned long long)col * 128 + p * 8);
            a0 += v * bflo(d.x);
            a1 += v * bfhi(d.x);
            a2 += v * bflo(d.y);
            a3 += v * bfhi(d.y);
        }
    }
#pragma unroll
    for (int o = 16; o < 64; o <<= 1) {
        a0 += __shfl_xor(a0, o, 64);
        a1 += __shfl_xor(a1, o, 64);
        a2 += __shfl_xor(a2, o, 64);
        a3 += __shfl_xor(a3, o, 64);
    }
    if (lane < 16) {
        ushort4 o4;
        o4.x = f2bf(a0); o4.y = f2bf(a1); o4.z = f2bf(a2); o4.w = f2bf(a3);
        *(ushort4*)&out[(long)node * 64 + p * 4] = o4;
    }
}

// ---------------- cache-blocked SpMM: only cols in [c0,c1) contribute ---------------
// Branchless filter (clamped gather to sup[c0], v=0) keeps 4 gathers pipelined.
// PHASE 0: write fp32 partials to scr. PHASE 2: add scr, emit bf16 to out.
// All concurrent waves share the same col window -> gather slice is L2-resident.
template<int F, int PHASE>
__global__ __launch_bounds__(256) void spmmc_k(const int* __restrict__ rp,
                                               const int* __restrict__ ecol,
                                               const float* __restrict__ ev,
                                               const unsigned short* __restrict__ sup,
                                               float* __restrict__ scr,
                                               unsigned short* __restrict__ out,
                                               int n, int c0, int c1) {
    constexpr int GL = F / 4;   // lanes per group
    constexpr int G  = 64 / GL; // edges per batch
    const int lane = threadIdx.x & 63;
    const int node = (blockIdx.x * blockDim.x + threadIdx.x) >> 6;
    if (node >= n) return;
    int s = __builtin_amdgcn_readfirstlane(rp[node]);
    int e = __builtin_amdgcn_readfirstlane(rp[node + 1]);
    const int g = lane / GL, p = lane % GL;
    float a0 = 0.f, a1 = 0.f, a2 = 0.f, a3 = 0.f;
    for (int i = s; i < e; i += 4 * G) {
#pragma unroll
        for (int b = 0; b < 4; ++b) {
            int idx = i + b * G + g;
            int cidx = idx < e ? idx : e - 1;  // e>s inside loop -> safe
            int col = ecol[cidx];
            float v = ev[cidx];
            bool keep = (idx < e) && (col >= c0) && (col < c1);
            if (!keep) v = 0.f;
            int gc = keep ? col : c0;
            uint2 d = *(const uint2*)((const char*)sup + (unsigned long long)gc * (F * 2) + p * 8);
            a0 += v * bflo(d.x);
            a1 += v * bfhi(d.x);
            a2 += v * bflo(d.y);
            a3 += v * bfhi(d.y);
        }
    }
#pragma unroll
    for (int o = GL; o < 64; o <<= 1) {
        a0 += __shfl_xor(a0, o, 64);
        a1 += __shfl_xor(a1, o, 64);
        a2 += __shfl_xor(a2, o, 64);
        a3 += __shfl_xor(a3, o, 64);
    }
    if (lane < GL) {
        long base = (long)node * F + p * 4;
        if (PHASE == 0) {
            *(float4*)&scr[base] = make_float4(a0, a1, a2, a3);
        } else {
            float4 pr = *(const float4*)&scr[base];
            a0 += pr.x; a1 += pr.y; a2 += pr.z; a3 += pr.w;
            ushort4 o4;
            o4.x = f2bf(a0); o4.y = f2bf(a1); o4.z = f2bf(a2); o4.w = f2bf(a3);
            *(ushort4*)&out[base] = o4;
        }
    }
}

// ---------------- layer-4 cache-blocked SpMM with fused BN+ELU, fp32 out ------------
// T[i][c] += sum_{e: col in [c0,c1)} val * elu(h[col][c]*scl[c]+sh[c]); F = 16.
template<int PHASE>
__global__ __launch_bounds__(256) void spmmf16c_k(const int* __restrict__ rp,
                                                  const int* __restrict__ ecol,
                                                  const float* __restrict__ ev,
                                                  const unsigned short* __restrict__ h,
                                                  const float* __restrict__ stats,
                                                  const float* __restrict__ gamma,
                                                  const float* __restrict__ beta,
                                                  float* __restrict__ out,
                                                  int n, int c0, int c1) {
    const int lane = threadIdx.x & 63;
    const int node = (blockIdx.x * blockDim.x + threadIdx.x) >> 6;
    if (node >= n) return;
    const int g = lane >> 2, p = lane & 3;  // 16 groups x 4 lanes
    float scl[4], sh[4];
#pragma unroll
    for (int j = 0; j < 4; ++j) {
        int c = p * 4 + j;
        float s1 = stats[c], s2 = stats[16 + c];
        float mean = s1 / (float)n;
        float var  = s2 / (float)n - mean * mean;
        float rstd = rsqrtf(var + 1e-5f);
        scl[j] = gamma[c] * rstd;
        sh[j]  = beta[c] - mean * scl[j];
    }
    int s = __builtin_amdgcn_readfirstlane(rp[node]);
    int e = __builtin_amdgcn_readfirstlane(rp[node + 1]);
    float a0 = 0.f, a1 = 0.f, a2 = 0.f, a3 = 0.f;
    for (int i = s; i < e; i += 64) {
#pragma unroll
        for (int b = 0; b < 4; ++b) {
            int idx = i + b * 16 + g;
            int cidx = idx < e ? idx : e - 1;  // e>s inside loop -> safe
            int col = ecol[cidx];
            float v = ev[cidx];
            bool keep = (idx < e) && (col >= c0) && (col < c1);
            if (!keep) v = 0.f;
            int gc = keep ? col : c0;
            uint2 d = *(const uint2*)((const char*)h + (unsigned long long)gc * 32 + p * 8);
            a0 += v * elu_f(bflo(d.x) * scl[0] + sh[0]);
            a1 += v * elu_f(bfhi(d.x) * scl[1] + sh[1]);
            a2 += v * elu_f(bflo(d.y) * scl[2] + sh[2]);
            a3 += v * elu_f(bfhi(d.y) * scl[3] + sh[3]);
        }
    }
#pragma unroll
    for (int o = 4; o < 64; o <<= 1) {
        a0 += __shfl_xor(a0, o, 64);
        a1 += __shfl_xor(a1, o, 64);
        a2 += __shfl_xor(a2, o, 64);
        a3 += __shfl_xor(a3, o, 64);
    }
    if (lane < 4) {
        long base = (long)node * 16 + p * 4;
        if (PHASE == 0) {
            *(float4*)&out[base] = make_float4(a0, a1, a2, a3);
        } else {
            float4 pr = *(const float4*)&out[base];
            *(float4*)&out[base] = make_float4(a0 + pr.x, a1 + pr.y, a2 + pr.z, a3 + pr.w);
        }
    }
}

// ---------------- final dense GEMM [N x 16](fp32) @ [16 x 40] + fused log_softmax ---
__global__ __launch_bounds__(256) void gemm4ls_k(const float* __restrict__ T,
                                                 const float* __restrict__ W4,
                                                 float* __restrict__ out, int n) {
    __shared__ __align__(16) float w[16 * 64];
    const int tid = threadIdx.x;
    for (int i = tid; i < 1024; i += 256) {
        int k = i >> 6, c = i & 63;
        w[i] = (c < 40) ? W4[k * 40 + c] : 0.f;
    }
    __syncthreads();
    const int grp = tid >> 4;          // 0..15: row within block
    const int p   = tid & 15;          // col group
    const int row = blockIdx.x * 16 + grp;
    if (row >= n) return;
    const float4* tp = (const float4*)(T + (long)row * 16);
    float4 t0 = tp[0], t1 = tp[1], t2 = tp[2], t3 = tp[3];
    float h[16] = {t0.x, t0.y, t0.z, t0.w, t1.x, t1.y, t1.z, t1.w,
                   t2.x, t2.y, t2.z, t2.w, t3.x, t3.y, t3.z, t3.w};
    float a0 = 0.f, a1 = 0.f, a2 = 0.f, a3 = 0.f;
#pragma unroll
    for (int k = 0; k < 16; ++k) {
        float4 wv = *(const float4*)&w[k * 64 + p * 4];
        a0 += h[k] * wv.x;
        a1 += h[k] * wv.y;
        a2 += h[k] * wv.z;
        a3 += h[k] * wv.w;
    }
    // log_softmax over 40 valid cols (p < 10)
    const bool valid = p < 10;
    float lm = valid ? fmaxf(fmaxf(a0, a1), fmaxf(a2, a3)) : -INFINITY;
#pragma unroll
    for (int o = 1; o < 16; o <<= 1) lm = fmaxf(lm, __shfl_xor(lm, o, 64));
    float ls = valid ? (expf(a0 - lm) + expf(a1 - lm) + expf(a2 - lm) + expf(a3 - lm)) : 0.f;
#pragma unroll
    for (int o = 1; o < 16; o <<= 1) ls += __shfl_xor(ls, o, 64);
    float lse = lm + logf(ls);
    if (valid) {
        float4 o4 = make_float4(a0 - lse, a1 - lse, a2 - lse, a3 - lse);
        *(float4*)&out[(long)row * 40 + p * 4] = o4;
    }
}

// ---------------- per-feature batch sums from bf16 h --------------------------------
template<int F>
__global__ __launch_bounds__(256) void statsb_k(const unsigned short* __restrict__ h,
                                                float* __restrict__ stats, int n) {
    __shared__ float m1[256], m2[256], m3[256], m4[256];
    const int tid = threadIdx.x;
    const unsigned int* h2 = (const unsigned int*)h;
    const long total = (long)n * F / 2;
    float s1 = 0.f, s2 = 0.f, t1 = 0.f, t2 = 0.f;
    for (long idx = (long)blockIdx.x * 256 + tid; idx < total; idx += (long)gridDim.x * 256) {
        unsigned int d = h2[idx];
        float lo = bflo(d), hi = bfhi(d);
        s1 += lo; s2 += lo * lo;
        t1 += hi; t2 += hi * hi;
    }
    m1[tid] = s1; m2[tid] = s2; m3[tid] = t1; m4[tid] = t2;
    __syncthreads();
    if (tid < F / 2) {
#pragma unroll 4
        for (int j = 1; j < 256 / (F / 2); ++j) {
            s1 += m1[tid + j * (F / 2)];
            s2 += m2[tid + j * (F / 2)];
            t1 += m3[tid + j * (F / 2)];
            t2 += m4[tid + j * (F / 2)];
        }
        atomicAdd(&stats[2 * tid], s1);
        atomicAdd(&stats[2 * tid + 1], t1);
        atomicAdd(&stats[F + 2 * tid], s2);
        atomicAdd(&stats[F + 2 * tid + 1], t2);
    }
}

extern "C" void kernel_launch(void* const* d_in, const int* in_sizes, int n_in,
                              void* d_out, int out_size, void* d_ws, size_t ws_size,
                              hipStream_t stream) {
    const float* x    = (const float*)d_in[0];
    const int*   erow = (const int*)d_in[1];
    const int*   ecol = (const int*)d_in[2];
    const float* ev   = (const float*)d_in[3];
    const float* W1   = (const float*)d_in[4];
    const float* W2   = (const float*)d_in[5];
    const float* W3   = (const float*)d_in[6];
    const float* W4   = (const float*)d_in[7];
    const float* g1   = (const float*)d_in[8];
    const float* b1   = (const float*)d_in[9];
    const float* g2   = (const float*)d_in[10];
    const float* b2   = (const float*)d_in[11];
    const float* g3   = (const float*)d_in[12];
    const float* b3   = (const float*)d_in[13];

    const int N = in_sizes[0] / 512;
    const int E = in_sizes[1];

    // workspace: rp | stats(256f) | Abf (N*64 bf16, also T as N*16 fp32) |
    //            Bbf (N*64 bf16) | Wb1 | Wb2 | Wb3 | scr (N*32 fp32)
    char* w = (char*)d_ws;
    int* rp = (int*)w;
    size_t off = (((size_t)(N + 1) * 4) + 255) & ~(size_t)255;
    float* stats = (float*)(w + off);
    unsigned short* Abf = (unsigned short*)(stats + 256);
    unsigned short* Bbf = Abf + (size_t)N * 64;
    unsigned short* Wb1 = Bbf + (size_t)N * 64;
    unsigned short* Wb2 = Wb1 + 64 * 512;
    unsigned short* Wb3 = Wb2 + 32 * 64;
    float* scr = (float*)((((size_t)(Wb3 + 16 * 32) + 255) & ~(size_t)255));
    float* Tf = (float*)Abf;  // N*16 fp32 = 6.4 MB, fits in Abf's 12.8 MB region
    float* outp = (float*)d_out;

    rowptr_k<<<(N + 1 + 255) / 256, 256, 0, stream>>>(erow, rp, N, E);
    zero_k<<<1, 256, 0, stream>>>(stats);
    w1bf_k<<<128, 256, 0, stream>>>(W1, Wb1);
    wsmall_k<<<8, 256, 0, stream>>>(W2, W3, Wb2, Wb3);

    const int mblocks = ((N + 15) / 16 + 3) / 4;
    const int sblocks = (N * 64 + 255) / 256;
    const int half = N / 2;

    // layer 1 (spmm64 = unbucketed control)
    gemm1_mfma_k<<<mblocks, 256, 0, stream>>>(x, Wb1, Abf, N);
    spmm64_k<<<sblocks, 256, 0, stream>>>(rp, ecol, ev, Abf, Bbf, N);
    statsb_k<64><<<512, 256, 0, stream>>>(Bbf, stats, N);

    // layer 2 (F=32, 2 col-buckets; slice 3.2 MB fits per-XCD L2)
    gemmS_k<64, 64, 2, 32><<<mblocks, 256, 0, stream>>>(Bbf, Wb2, stats, g1, b1, Abf, N);
    spmmc_k<32, 0><<<sblocks, 256, 0, stream>>>(rp, ecol, ev, Abf, scr, Bbf, N, 0, half);
    spmmc_k<32, 2><<<sblocks, 256, 0, stream>>>(rp, ecol, ev, Abf, scr, Bbf, N, half, N);
    statsb_k<32><<<512, 256, 0, stream>>>(Bbf, stats + 128, N);

    // layer 3 (F=16, 2 col-buckets; slice 1.6 MB)
    gemmS_k<32, 32, 1, 16><<<mblocks, 256, 0, stream>>>(Bbf, Wb3, stats + 128, g2, b2, Abf, N);
    spmmc_k<16, 0><<<sblocks, 256, 0, stream>>>(rp, ecol, ev, Abf, scr, Bbf, N, 0, half);
    spmmc_k<16, 2><<<sblocks, 256, 0, stream>>>(rp, ecol, ev, Abf, scr, Bbf, N, half, N);
    statsb_k<16><<<512, 256, 0, stream>>>(Bbf, stats + 192, N);

    // layer 4, commuted: T = A·f3(H3) with BN+ELU fused into the bucketed gather,
    // fp32 accumulate in Tf, then tiny dense GEMM + log_softmax.
    spmmf16c_k<0><<<sblocks, 256, 0, stream>>>(rp, ecol, ev, Bbf, stats + 192, g3, b3, Tf, N, 0, half);
    spmmf16c_k<2><<<sblocks, 256, 0, stream>>>(rp, ecol, ev, Bbf, stats + 192, g3, b3, Tf, N, half, N);
    gemm4ls_k<<<(N + 15) / 16, 256, 0, stream>>>(Tf, W4, outp, N);
}

// Round 7
// 680.605 us; speedup vs baseline: 1.2212x; 1.2212x over previous
//
#include <hip/hip_runtime.h>
#include <hip/hip_bf16.h>
#include <math.h>

typedef __attribute__((ext_vector_type(8))) short short8;
typedef __attribute__((ext_vector_type(4))) float floatx4;

__device__ __forceinline__ float elu_f(float t) {
    return t > 0.f ? t : expm1f(t);
}

__device__ __forceinline__ unsigned short f2bf(float f) {
    unsigned int u = __float_as_uint(f);
    u = (u + 0x7FFFu + ((u >> 16) & 1u)) >> 16;
    return (unsigned short)u;
}

// pack two fp32 -> packed bf16x2 (lo in low half), RNE
__device__ __forceinline__ unsigned int f2bf2(float lo, float hi) {
    unsigned int a = __float_as_uint(lo);
    unsigned int b = __float_as_uint(hi);
    a = (a + 0x7FFFu + ((a >> 16) & 1u)) >> 16;
    b = (b + 0x7FFFu + ((b >> 16) & 1u)) & 0xFFFF0000u;
    return a | b;
}

__device__ __forceinline__ float bflo(unsigned int d) { return __uint_as_float(d << 16); }
__device__ __forceinline__ float bfhi(unsigned int d) { return __uint_as_float(d & 0xFFFF0000u); }

// ---------------- fused prep: rowptr | stats-zero | W1->bf16^T | W2/W3->bf16^T ------
// Block-range partitioned single launch (replaces 4 tiny launches).
__global__ __launch_bounds__(256) void prep_k(const int* __restrict__ erow,
                                              const float* __restrict__ W1,
                                              const float* __restrict__ W2,
                                              const float* __restrict__ W3,
                                              int* __restrict__ rp,
                                              float* __restrict__ stats,
                                              unsigned short* __restrict__ Wb1,
                                              unsigned short* __restrict__ Wb2,
                                              unsigned short* __restrict__ Wb3,
                                              int n, int e, int nb_rp) {
    const int b = blockIdx.x;
    const int tid = threadIdx.x;
    if (b < nb_rp) {                       // rowptr: lower_bound per node
        int i = b * 256 + tid;
        if (i > n) return;
        int lo = 0, hi = e;
        while (lo < hi) {
            int mid = (lo + hi) >> 1;
            if (erow[mid] < i) lo = mid + 1; else hi = mid;
        }
        rp[i] = lo;
    } else if (b < nb_rp + 128) {          // W1 -> bf16 transposed [64][512]
        int idx = (b - nb_rp) * 256 + tid;  // 0..32767
        int nn = idx >> 9, k = idx & 511;
        Wb1[idx] = f2bf(W1[(long)k * 64 + nn]);
    } else if (b < nb_rp + 136) {          // W2/W3 -> bf16 transposed
        int idx = (b - nb_rp - 128) * 256 + tid;  // 0..2047
        if (idx < 2048) {  // Wb2: [32][64]
            int nn = idx >> 6, k = idx & 63;
            Wb2[idx] = f2bf(W2[(long)k * 32 + nn]);
        }
        if (idx < 512) {   // Wb3: [16][32]
            int nn = idx >> 5, k = idx & 31;
            Wb3[idx] = f2bf(W3[(long)k * 16 + nn]);
        }
    } else {                               // zero stats
        if (tid < 224) stats[tid] = 0.f;
    }
}

// ---------------- GEMM1 (MFMA bf16, streaming): Abf[N x 64] = X @ W1 ----------------
__global__ __launch_bounds__(256) void gemm1_mfma_k(const float* __restrict__ X,
                                                    const unsigned short* __restrict__ Wb,
                                                    unsigned short* __restrict__ out, int nrows) {
    const int lane = threadIdx.x & 63;
    const int wid  = threadIdx.x >> 6;
    const int lrow = lane & 15;
    const int quad = lane >> 4;
    const int m0   = (blockIdx.x * 4 + wid) * 16;
    if (m0 >= nrows) return;  // wave-uniform

    int arow = m0 + lrow;
    if (arow >= nrows) arow = nrows - 1;
    const float* __restrict__ xrow = X + (long)arow * 512 + quad * 8;
    const unsigned short* __restrict__ brow = Wb + lrow * 512 + quad * 8;

    floatx4 acc[4];
#pragma unroll
    for (int ni = 0; ni < 4; ++ni) acc[ni] = (floatx4){0.f, 0.f, 0.f, 0.f};

    float4 ca0 = *(const float4*)(xrow + 0);
    float4 ca1 = *(const float4*)(xrow + 4);
    short8 cb[4];
#pragma unroll
    for (int ni = 0; ni < 4; ++ni) cb[ni] = *(const short8*)(brow + ni * 8192);

#pragma unroll
    for (int kc = 0; kc < 16; ++kc) {
        float4 na0, na1;
        short8 nb[4];
        if (kc < 15) {
            const float* xp = xrow + (kc + 1) * 32;
            na0 = *(const float4*)(xp + 0);
            na1 = *(const float4*)(xp + 4);
#pragma unroll
            for (int ni = 0; ni < 4; ++ni)
                nb[ni] = *(const short8*)(brow + ni * 8192 + (kc + 1) * 32);
        }
        union { short8 s; unsigned int u[4]; } af;
        af.u[0] = f2bf2(ca0.x, ca0.y);
        af.u[1] = f2bf2(ca0.z, ca0.w);
        af.u[2] = f2bf2(ca1.x, ca1.y);
        af.u[3] = f2bf2(ca1.z, ca1.w);
#pragma unroll
        for (int ni = 0; ni < 4; ++ni)
            acc[ni] = __builtin_amdgcn_mfma_f32_16x16x32_bf16(af.s, cb[ni], acc[ni], 0, 0, 0);
        if (kc < 15) {
            ca0 = na0; ca1 = na1;
#pragma unroll
            for (int ni = 0; ni < 4; ++ni) cb[ni] = nb[ni];
        }
    }

    // C/D layout: col = lane&15, row = quad*4 + reg
#pragma unroll
    for (int r = 0; r < 4; ++r) {
        int gr = m0 + quad * 4 + r;
        if (gr < nrows) {
#pragma unroll
            for (int ni = 0; ni < 4; ++ni)
                out[(long)gr * 64 + ni * 16 + lrow] = f2bf(acc[ni][r]);
        }
    }
}

// ---------------- layers 2-3: streaming MFMA bf16 with fused BN+ELU on input --------
// out[N x NSTR] (bf16) = bn_elu(H[N x K]) @ W[K x NC], Wb transposed [NF*16][KP] bf16.
template<int K, int KP, int NF, int NSTR>
__global__ __launch_bounds__(256) void gemmS_k(const unsigned short* __restrict__ H,
                                               const unsigned short* __restrict__ Wb,
                                               const float* __restrict__ stats,
                                               const float* __restrict__ gamma,
                                               const float* __restrict__ beta,
                                               unsigned short* __restrict__ out,
                                               int nrows) {
    __shared__ __align__(16) float scs[K];
    __shared__ __align__(16) float shs[K];
    const int tid = threadIdx.x;
    if (tid < K) {
        float s1 = stats[tid], s2 = stats[K + tid];
        float mean = s1 / (float)nrows;
        float var  = s2 / (float)nrows - mean * mean;
        float rstd = rsqrtf(var + 1e-5f);
        float scl  = gamma[tid] * rstd;
        scs[tid] = scl;
        shs[tid] = beta[tid] - mean * scl;
    }
    __syncthreads();

    const int lane = tid & 63;
    const int wid  = tid >> 6;
    const int lrow = lane & 15;
    const int quad = lane >> 4;
    const int m0   = (blockIdx.x * 4 + wid) * 16;
    if (m0 >= nrows) return;  // after barrier: safe

    int arow = m0 + lrow;
    if (arow >= nrows) arow = nrows - 1;
    const unsigned short* __restrict__ hrow = H + (long)arow * K;

    floatx4 acc[NF];
#pragma unroll
    for (int ni = 0; ni < NF; ++ni) acc[ni] = (floatx4){0.f, 0.f, 0.f, 0.f};

#pragma unroll
    for (int kc = 0; kc < KP; kc += 32) {
        const int k8 = kc + quad * 8;
        union { short8 s; unsigned int u[4]; } af;
        if (k8 < K) {
            uint4 d = *(const uint4*)(hrow + k8);
            float4 sc0 = *(const float4*)&scs[k8];
            float4 sc1 = *(const float4*)&scs[k8 + 4];
            float4 sh0 = *(const float4*)&shs[k8];
            float4 sh1 = *(const float4*)&shs[k8 + 4];
            float f0 = elu_f(bflo(d.x) * sc0.x + sh0.x);
            float f1 = elu_f(bfhi(d.x) * sc0.y + sh0.y);
            float f2 = elu_f(bflo(d.y) * sc0.z + sh0.z);
            float f3 = elu_f(bfhi(d.y) * sc0.w + sh0.w);
            float f4 = elu_f(bflo(d.z) * sc1.x + sh1.x);
            float f5 = elu_f(bfhi(d.z) * sc1.y + sh1.y);
            float f6 = elu_f(bflo(d.w) * sc1.z + sh1.z);
            float f7 = elu_f(bfhi(d.w) * sc1.w + sh1.w);
            af.u[0] = f2bf2(f0, f1);
            af.u[1] = f2bf2(f2, f3);
            af.u[2] = f2bf2(f4, f5);
            af.u[3] = f2bf2(f6, f7);
        } else {
            af.u[0] = af.u[1] = af.u[2] = af.u[3] = 0u;
        }
#pragma unroll
        for (int ni = 0; ni < NF; ++ni) {
            short8 bf = *(const short8*)&Wb[(ni * 16 + lrow) * KP + k8];
            acc[ni] = __builtin_amdgcn_mfma_f32_16x16x32_bf16(af.s, bf, acc[ni], 0, 0, 0);
        }
    }

#pragma unroll
    for (int r = 0; r < 4; ++r) {
        int gr = m0 + quad * 4 + r;
        if (gr < nrows) {
#pragma unroll
            for (int ni = 0; ni < NF; ++ni)
                out[(long)gr * NSTR + ni * 16 + lrow] = f2bf(acc[ni][r]);
        }
    }
}

// ---------------- SpMM bf16: out[i][c] = sum val * sup[col][c]; 1 node per wave -----
// Wave = G groups x GL lanes; each lane loads 4 bf16 (8 B); G edges per batch, 4
// batches unrolled -> 4 independent gathers in flight; cross-group shuffle reduce.
template<int F>
__global__ __launch_bounds__(256) void spmmb_k(const int* __restrict__ rp,
                                               const int* __restrict__ ecol,
                                               const float* __restrict__ ev,
                                               const unsigned short* __restrict__ sup,
                                               unsigned short* __restrict__ out, int n) {
    constexpr int GL = F / 4;   // lanes per group
    constexpr int G  = 64 / GL; // edges per batch
    const int lane = threadIdx.x & 63;
    const int node = (blockIdx.x * blockDim.x + threadIdx.x) >> 6;
    if (node >= n) return;
    int s = __builtin_amdgcn_readfirstlane(rp[node]);
    int e = __builtin_amdgcn_readfirstlane(rp[node + 1]);
    const int g = lane / GL, p = lane % GL;
    float a0 = 0.f, a1 = 0.f, a2 = 0.f, a3 = 0.f;
    for (int i = s; i < e; i += 4 * G) {
#pragma unroll
        for (int b = 0; b < 4; ++b) {
            int idx = i + b * G + g;
            int cidx = idx < e ? idx : e - 1;  // e>s inside loop -> safe
            int col = ecol[cidx];
            float v = ev[cidx];
            if (idx >= e) v = 0.f;
            uint2 d = *(const uint2*)((const char*)sup + (unsigned long long)col * (F * 2) + p * 8);
            a0 += v * bflo(d.x);
            a1 += v * bfhi(d.x);
            a2 += v * bflo(d.y);
            a3 += v * bfhi(d.y);
        }
    }
#pragma unroll
    for (int o = GL; o < 64; o <<= 1) {
        a0 += __shfl_xor(a0, o, 64);
        a1 += __shfl_xor(a1, o, 64);
        a2 += __shfl_xor(a2, o, 64);
        a3 += __shfl_xor(a3, o, 64);
    }
    if (lane < GL) {
        ushort4 o4;
        o4.x = f2bf(a0); o4.y = f2bf(a1); o4.z = f2bf(a2); o4.w = f2bf(a3);
        *(ushort4*)&out[(long)node * F + p * 4] = o4;
    }
}

// ---------------- layer-4 SpMM with fused BN+ELU on the gathered rows ---------------
// T[i][c] (fp32) = sum_e val * elu(h[col][c]*scl[c] + sh[c]); F = 16.
__global__ __launch_bounds__(256) void spmmf16_k(const int* __restrict__ rp,
                                                 const int* __restrict__ ecol,
                                                 const float* __restrict__ ev,
                                                 const unsigned short* __restrict__ h,
                                                 const float* __restrict__ stats,
                                                 const float* __restrict__ gamma,
                                                 const float* __restrict__ beta,
                                                 float* __restrict__ out, int n) {
    const int lane = threadIdx.x & 63;
    const int node = (blockIdx.x * blockDim.x + threadIdx.x) >> 6;
    if (node >= n) return;
    const int g = lane >> 2, p = lane & 3;  // 16 groups x 4 lanes; lane owns feats 4p..4p+3
    float scl[4], sh[4];
#pragma unroll
    for (int j = 0; j < 4; ++j) {
        int c = p * 4 + j;
        float s1 = stats[c], s2 = stats[16 + c];
        float mean = s1 / (float)n;
        float var  = s2 / (float)n - mean * mean;
        float rstd = rsqrtf(var + 1e-5f);
        scl[j] = gamma[c] * rstd;
        sh[j]  = beta[c] - mean * scl[j];
    }
    int s = __builtin_amdgcn_readfirstlane(rp[node]);
    int e = __builtin_amdgcn_readfirstlane(rp[node + 1]);
    float a0 = 0.f, a1 = 0.f, a2 = 0.f, a3 = 0.f;
    for (int i = s; i < e; i += 64) {
#pragma unroll
        for (int b = 0; b < 4; ++b) {
            int idx = i + b * 16 + g;
            int cidx = idx < e ? idx : e - 1;  // e>s inside loop -> safe
            int col = ecol[cidx];
            float v = ev[cidx];
            if (idx >= e) v = 0.f;
            uint2 d = *(const uint2*)((const char*)h + (unsigned long long)col * 32 + p * 8);
            a0 += v * elu_f(bflo(d.x) * scl[0] + sh[0]);
            a1 += v * elu_f(bfhi(d.x) * scl[1] + sh[1]);
            a2 += v * elu_f(bflo(d.y) * scl[2] + sh[2]);
            a3 += v * elu_f(bfhi(d.y) * scl[3] + sh[3]);
        }
    }
#pragma unroll
    for (int o = 4; o < 64; o <<= 1) {
        a0 += __shfl_xor(a0, o, 64);
        a1 += __shfl_xor(a1, o, 64);
        a2 += __shfl_xor(a2, o, 64);
        a3 += __shfl_xor(a3, o, 64);
    }
    if (lane < 4) {
        float4 o4 = make_float4(a0, a1, a2, a3);
        *(float4*)&out[(long)node * 16 + p * 4] = o4;
    }
}

// ---------------- final dense GEMM [N x 16](fp32) @ [16 x 40] + fused log_softmax ---
__global__ __launch_bounds__(256) void gemm4ls_k(const float* __restrict__ T,
                                                 const float* __restrict__ W4,
                                                 float* __restrict__ out, int n) {
    __shared__ __align__(16) float w[16 * 64];
    const int tid = threadIdx.x;
    for (int i = tid; i < 1024; i += 256) {
        int k = i >> 6, c = i & 63;
        w[i] = (c < 40) ? W4[k * 40 + c] : 0.f;
    }
    __syncthreads();
    const int grp = tid >> 4;          // 0..15: row within block
    const int p   = tid & 15;          // col group
    const int row = blockIdx.x * 16 + grp;
    if (row >= n) return;
    const float4* tp = (const float4*)(T + (long)row * 16);
    float4 t0 = tp[0], t1 = tp[1], t2 = tp[2], t3 = tp[3];
    float h[16] = {t0.x, t0.y, t0.z, t0.w, t1.x, t1.y, t1.z, t1.w,
                   t2.x, t2.y, t2.z, t2.w, t3.x, t3.y, t3.z, t3.w};
    float a0 = 0.f, a1 = 0.f, a2 = 0.f, a3 = 0.f;
#pragma unroll
    for (int k = 0; k < 16; ++k) {
        float4 wv = *(const float4*)&w[k * 64 + p * 4];
        a0 += h[k] * wv.x;
        a1 += h[k] * wv.y;
        a2 += h[k] * wv.z;
        a3 += h[k] * wv.w;
    }
    // log_softmax over 40 valid cols (p < 10)
    const bool valid = p < 10;
    float lm = valid ? fmaxf(fmaxf(a0, a1), fmaxf(a2, a3)) : -INFINITY;
#pragma unroll
    for (int o = 1; o < 16; o <<= 1) lm = fmaxf(lm, __shfl_xor(lm, o, 64));
    float ls = valid ? (expf(a0 - lm) + expf(a1 - lm) + expf(a2 - lm) + expf(a3 - lm)) : 0.f;
#pragma unroll
    for (int o = 1; o < 16; o <<= 1) ls += __shfl_xor(ls, o, 64);
    float lse = lm + logf(ls);
    if (valid) {
        float4 o4 = make_float4(a0 - lse, a1 - lse, a2 - lse, a3 - lse);
        *(float4*)&out[(long)row * 40 + p * 4] = o4;
    }
}

// ---------------- per-feature batch sums from bf16 h --------------------------------
template<int F>
__global__ __launch_bounds__(256) void statsb_k(const unsigned short* __restrict__ h,
                                                float* __restrict__ stats, int n) {
    __shared__ float m1[256], m2[256], m3[256], m4[256];
    const int tid = threadIdx.x;
    const unsigned int* h2 = (const unsigned int*)h;
    const long total = (long)n * F / 2;
    float s1 = 0.f, s2 = 0.f, t1 = 0.f, t2 = 0.f;
    for (long idx = (long)blockIdx.x * 256 + tid; idx < total; idx += (long)gridDim.x * 256) {
        unsigned int d = h2[idx];
        float lo = bflo(d), hi = bfhi(d);
        s1 += lo; s2 += lo * lo;
        t1 += hi; t2 += hi * hi;
    }
    m1[tid] = s1; m2[tid] = s2; m3[tid] = t1; m4[tid] = t2;
    __syncthreads();
    if (tid < F / 2) {
#pragma unroll 4
        for (int j = 1; j < 256 / (F / 2); ++j) {
            s1 += m1[tid + j * (F / 2)];
            s2 += m2[tid + j * (F / 2)];
            t1 += m3[tid + j * (F / 2)];
            t2 += m4[tid + j * (F / 2)];
        }
        atomicAdd(&stats[2 * tid], s1);
        atomicAdd(&stats[2 * tid + 1], t1);
        atomicAdd(&stats[F + 2 * tid], s2);
        atomicAdd(&stats[F + 2 * tid + 1], t2);
    }
}

extern "C" void kernel_launch(void* const* d_in, const int* in_sizes, int n_in,
                              void* d_out, int out_size, void* d_ws, size_t ws_size,
                              hipStream_t stream) {
    const float* x    = (const float*)d_in[0];
    const int*   erow = (const int*)d_in[1];
    const int*   ecol = (const int*)d_in[2];
    const float* ev   = (const float*)d_in[3];
    const float* W1   = (const float*)d_in[4];
    const float* W2   = (const float*)d_in[5];
    const float* W3   = (const float*)d_in[6];
    const float* W4   = (const float*)d_in[7];
    const float* g1   = (const float*)d_in[8];
    const float* b1   = (const float*)d_in[9];
    const float* g2   = (const float*)d_in[10];
    const float* b2   = (const float*)d_in[11];
    const float* g3   = (const float*)d_in[12];
    const float* b3   = (const float*)d_in[13];

    const int N = in_sizes[0] / 512;
    const int E = in_sizes[1];

    // workspace: rp | stats(256f) | Abf (N*64 bf16, also holds T as N*16 fp32) |
    //            Bbf (N*64 bf16) | Wb1 | Wb2 | Wb3
    char* w = (char*)d_ws;
    int* rp = (int*)w;
    size_t off = (((size_t)(N + 1) * 4) + 255) & ~(size_t)255;
    float* stats = (float*)(w + off);
    unsigned short* Abf = (unsigned short*)(stats + 256);
    unsigned short* Bbf = Abf + (size_t)N * 64;
    unsigned short* Wb1 = Bbf + (size_t)N * 64;
    unsigned short* Wb2 = Wb1 + 64 * 512;
    unsigned short* Wb3 = Wb2 + 32 * 64;
    float* Tf = (float*)Abf;  // N*16 fp32 = 6.4 MB, fits in Abf's 12.8 MB region
    float* outp = (float*)d_out;

    // fused prep (rowptr + stats-zero + weight transposes) in one launch
    const int nb_rp = (N + 1 + 255) / 256;
    prep_k<<<nb_rp + 128 + 8 + 1, 256, 0, stream>>>(erow, W1, W2, W3, rp, stats,
                                                    Wb1, Wb2, Wb3, N, E, nb_rp);

    const int mblocks = ((N + 15) / 16 + 3) / 4;
    const int sblocks = (N * 64 + 255) / 256;

    // layer 1
    gemm1_mfma_k<<<mblocks, 256, 0, stream>>>(x, Wb1, Abf, N);
    spmmb_k<64><<<sblocks, 256, 0, stream>>>(rp, ecol, ev, Abf, Bbf, N);
    statsb_k<64><<<512, 256, 0, stream>>>(Bbf, stats, N);

    // layer 2
    gemmS_k<64, 64, 2, 32><<<mblocks, 256, 0, stream>>>(Bbf, Wb2, stats, g1, b1, Abf, N);
    spmmb_k<32><<<sblocks, 256, 0, stream>>>(rp, ecol, ev, Abf, Bbf, N);
    statsb_k<32><<<512, 256, 0, stream>>>(Bbf, stats + 128, N);

    // layer 3
    gemmS_k<32, 32, 1, 16><<<mblocks, 256, 0, stream>>>(Bbf, Wb3, stats + 128, g2, b2, Abf, N);
    spmmb_k<16><<<sblocks, 256, 0, stream>>>(rp, ecol, ev, Abf, Bbf, N);
    statsb_k<16><<<512, 256, 0, stream>>>(Bbf, stats + 192, N);

    // layer 4, commuted: A·(f(H3)@W4) = (A·f(H3))@W4 — BN+ELU fused into the gather,
    // aggregate kept fp32, then tiny dense GEMM + log_softmax.
    spmmf16_k<<<sblocks, 256, 0, stream>>>(rp, ecol, ev, Bbf, stats + 192, g3, b3, Tf, N);
    gemm4ls_k<<<(N + 15) / 16, 256, 0, stream>>>(Tf, W4, outp, N);
}